// Round 1
// baseline (1061.014 us; speedup 1.0000x reference)
//
#include <hip/hip_runtime.h>

// Problem: B=2, H=16, S=2048, DK=DV=64, fp32.
// out = [context (B,H,S,64) | attention (B,H,S,S)] flat-concatenated.
// Softmax has no max-subtraction: scores bounded (~|s|<8), exp() safe in fp32,
// and exp(s)/sum matches jax.nn.softmax to fp32 rounding.
// Mask: int32 (bool->int), shape (B,1,S,S); mask==0 => score := 1e-9 (NOT -inf).

#define S_LEN 2048
#define DKV 64
#define NBH 32      // B*H
#define NH 16       // H
#define TILE 64
#define PAD 4       // LDS pad: stride 68 floats = 272B (16B-aligned, 2-way banks only)

__global__ __launch_bounds__(256) void attn_p_kernel(
    const float* __restrict__ q, const float* __restrict__ k,
    const int* __restrict__ mask, float* __restrict__ attn,
    float* __restrict__ rowsum)
{
    __shared__ float Qts[TILE][TILE + PAD];  // [kk][q_row]  (transposed)
    __shared__ float Kts[TILE][TILE + PAD];  // [kk][k_row]  (transposed)

    const int kt = blockIdx.x;   // k tile (0..31)
    const int qt = blockIdx.y;   // q tile (0..31)
    const int bh = blockIdx.z;   // b*H + h (0..31)
    const int t  = threadIdx.x;
    const int tx = t & 15;       // score col group
    const int ty = t >> 4;       // score row group

    // Q tile and K tile are each a contiguous 4096-float block (row stride = DK = 64).
    const float* qbase = q + (size_t)(bh * S_LEN + qt * TILE) * DKV;
    const float* kbase = k + (size_t)(bh * S_LEN + kt * TILE) * DKV;
#pragma unroll
    for (int j = 0; j < 4; ++j) {
        const int f   = (t + 256 * j) * 4;
        const int row = f >> 6;
        const int c   = f & 63;
        const float4 a4 = *(const float4*)(qbase + f);
        Qts[c + 0][row] = a4.x; Qts[c + 1][row] = a4.y;
        Qts[c + 2][row] = a4.z; Qts[c + 3][row] = a4.w;
        const float4 b4 = *(const float4*)(kbase + f);
        Kts[c + 0][row] = b4.x; Kts[c + 1][row] = b4.y;
        Kts[c + 2][row] = b4.z; Kts[c + 3][row] = b4.w;
    }
    __syncthreads();

    float acc[4][4] = {};
#pragma unroll 8
    for (int kk = 0; kk < 64; ++kk) {
        const float4 a4 = *(const float4*)&Qts[kk][4 * ty];
        const float4 b4 = *(const float4*)&Kts[kk][4 * tx];
        const float a[4] = {a4.x, a4.y, a4.z, a4.w};
        const float b[4] = {b4.x, b4.y, b4.z, b4.w};
#pragma unroll
        for (int i = 0; i < 4; ++i)
#pragma unroll
            for (int j = 0; j < 4; ++j)
                acc[i][j] = fmaf(a[i], b[j], acc[i][j]);
    }

    // Epilogue: scale, mask, exp, store P, row partial sums.
    const float scale = 0.125f;  // 1/sqrt(64)
    const int b_idx = bh >> 4;   // bh / H
    const int kc = kt * TILE + 4 * tx;
    float partial[4];
#pragma unroll
    for (int i = 0; i < 4; ++i) {
        const int qr = qt * TILE + 4 * ty + i;
        const int4 m4 = *(const int4*)(mask + (size_t)b_idx * S_LEN * S_LEN
                                            + (size_t)qr * S_LEN + kc);
        float s0 = acc[i][0] * scale; if (m4.x == 0) s0 = 1e-9f;
        float s1 = acc[i][1] * scale; if (m4.y == 0) s1 = 1e-9f;
        float s2 = acc[i][2] * scale; if (m4.z == 0) s2 = 1e-9f;
        float s3 = acc[i][3] * scale; if (m4.w == 0) s3 = 1e-9f;
        float4 p4;
        p4.x = __expf(s0); p4.y = __expf(s1); p4.z = __expf(s2); p4.w = __expf(s3);
        *(float4*)(attn + ((size_t)(bh * S_LEN) + qr) * S_LEN + kc) = p4;
        partial[i] = (p4.x + p4.y) + (p4.z + p4.w);
    }
    // Reduce partials across the 16 tx lanes (contiguous lane groups within a wave).
#pragma unroll
    for (int i = 0; i < 4; ++i) {
#pragma unroll
        for (int off = 8; off > 0; off >>= 1)
            partial[i] += __shfl_down(partial[i], off, 16);
    }
    if (tx == 0) {
#pragma unroll
        for (int i = 0; i < 4; ++i)
            atomicAdd(&rowsum[bh * S_LEN + qt * TILE + 4 * ty + i], partial[i]);
    }
}

__global__ __launch_bounds__(256) void attn_ctx_kernel(
    const float* __restrict__ v, float* __restrict__ attn,
    const float* __restrict__ rowsum, float* __restrict__ ctx)
{
    __shared__ float Pts[TILE][TILE + PAD];  // [kk][q_row] (transposed, normalized P)
    __shared__ float Vs[TILE][TILE + PAD];   // [kk][d_col]
    __shared__ float rinv[TILE];

    const int qt = blockIdx.x;   // q tile (0..31)
    const int bh = blockIdx.y;   // 0..31
    const int t  = threadIdx.x;
    const int tx = t & 15;       // d col group
    const int ty = t >> 4;       // q row group

    if (t < TILE)
        rinv[t] = 1.0f / rowsum[bh * S_LEN + qt * TILE + t];
    __syncthreads();

    float acc[4][4] = {};
    for (int kt = 0; kt < S_LEN / TILE; ++kt) {
        const float* vbase = v + (size_t)(bh * S_LEN + kt * TILE) * DKV;  // contiguous tile
#pragma unroll
        for (int j = 0; j < 4; ++j) {
            const int f   = (t + 256 * j) * 4;
            const int row = f >> 6;
            const int c   = f & 63;
            // P tile: row-major in attn, row stride S.
            float* pp = attn + ((size_t)(bh * S_LEN) + qt * TILE + row) * S_LEN
                             + kt * TILE + c;
            float4 p4 = *(const float4*)pp;
            const float r = rinv[row];
            p4.x *= r; p4.y *= r; p4.z *= r; p4.w *= r;
            *(float4*)pp = p4;   // write normalized attention in place
            Pts[c + 0][row] = p4.x; Pts[c + 1][row] = p4.y;
            Pts[c + 2][row] = p4.z; Pts[c + 3][row] = p4.w;
            // V tile: contiguous; f = kk*64 + col.
            *(float4*)&Vs[row][c] = *(const float4*)(vbase + f);
        }
        __syncthreads();
#pragma unroll 8
        for (int kk = 0; kk < 64; ++kk) {
            const float4 a4 = *(const float4*)&Pts[kk][4 * ty];
            const float4 b4 = *(const float4*)&Vs[kk][4 * tx];
            const float a[4] = {a4.x, a4.y, a4.z, a4.w};
            const float b[4] = {b4.x, b4.y, b4.z, b4.w};
#pragma unroll
            for (int i = 0; i < 4; ++i)
#pragma unroll
                for (int j = 0; j < 4; ++j)
                    acc[i][j] = fmaf(a[i], b[j], acc[i][j]);
        }
        __syncthreads();
    }

#pragma unroll
    for (int i = 0; i < 4; ++i) {
        const int qr = qt * TILE + 4 * ty + i;
        float4 c4;
        c4.x = acc[i][0]; c4.y = acc[i][1]; c4.z = acc[i][2]; c4.w = acc[i][3];
        *(float4*)(ctx + ((size_t)(bh * S_LEN) + qr) * DKV + 4 * tx) = c4;
    }
}

extern "C" void kernel_launch(void* const* d_in, const int* in_sizes, int n_in,
                              void* d_out, int out_size, void* d_ws, size_t ws_size,
                              hipStream_t stream) {
    const float* q    = (const float*)d_in[0];
    const float* k    = (const float*)d_in[1];
    const float* v    = (const float*)d_in[2];
    const int*   mask = (const int*)d_in[3];

    float* out  = (float*)d_out;
    float* ctx  = out;                                  // (B,H,S,64)
    float* attn = out + (size_t)NBH * S_LEN * DKV;      // (B,H,S,S)
    float* rowsum = (float*)d_ws;                       // NBH*S floats = 256 KB

    hipMemsetAsync(rowsum, 0, (size_t)NBH * S_LEN * sizeof(float), stream);

    attn_p_kernel<<<dim3(S_LEN / TILE, S_LEN / TILE, NBH), 256, 0, stream>>>(
        q, k, mask, attn, rowsum);
    attn_ctx_kernel<<<dim3(S_LEN / TILE, NBH), 256, 0, stream>>>(
        v, attn, rowsum, ctx);
}